// Round 2
// baseline (332.221 us; speedup 1.0000x reference)
//
#include <hip/hip_runtime.h>
#include <stdint.h>

#define CC 256
#define NN 4096   // H*W = 64*64

typedef __attribute__((ext_vector_type(8))) short short8;
typedef __attribute__((ext_vector_type(4))) float floatx4;
typedef __attribute__((ext_vector_type(4))) unsigned int uint4v;

__device__ __forceinline__ unsigned short f2bf(float f) {
    unsigned int u = __builtin_bit_cast(unsigned int, f);
    u = (u + 0x7FFFu + ((u >> 16) & 1u)) >> 16;   // RNE
    return (unsigned short)u;
}

__device__ __forceinline__ floatx4 mfma16(short8 a, short8 b, floatx4 c) {
    return __builtin_amdgcn_mfma_f32_16x16x32_bf16(a, b, c, 0, 0, 0);
}

// ---------------------------------------------------------------------------
// k_trans: xT[b][n][c] = bf16(x[b][c][n])  (64x64 LDS tile transpose)
//          + per-block partial norms: psum[b][n][cc] = sum_{c in chunk} x^2
// grid 1024 blocks (b*4cc*64nc) x 256 thr
// ---------------------------------------------------------------------------
__global__ __launch_bounds__(256) void k_trans(const float* __restrict__ x,
                                               unsigned short* __restrict__ xT,
                                               float* __restrict__ psum) {
    int blk = blockIdx.x;
    int b  = blk >> 8;
    int cc = (blk >> 6) & 3;
    int nc = blk & 63;
    int c0 = cc << 6, n0 = nc << 6;
    __shared__ float tile[64][65];     // +1 pad: conflict-free column reads
    __shared__ float red[4][64];
    int t = threadIdx.x;
    {
        int c   = t >> 2;
        int nn4 = (t & 3) << 4;
        const float* src = x + (size_t)(b * CC + c0 + c) * NN + n0 + nn4;
        #pragma unroll
        for (int j = 0; j < 16; j += 4) {
            floatx4 v = *(const floatx4*)(src + j);
            tile[c][nn4 + j + 0] = v[0];
            tile[c][nn4 + j + 1] = v[1];
            tile[c][nn4 + j + 2] = v[2];
            tile[c][nn4 + j + 3] = v[3];
        }
    }
    __syncthreads();
    // transpose -> bf16 xT
    {
        int n  = t >> 2;
        int ci = (t & 3) << 4;
        unsigned short* dst = xT + (size_t)(b * NN + n0 + n) * CC + c0 + ci;
        unsigned int w[8];
        #pragma unroll
        for (int j = 0; j < 8; ++j) {
            unsigned int lo = f2bf(tile[ci + 2 * j][n]);
            unsigned int hi = f2bf(tile[ci + 2 * j + 1][n]);
            w[j] = lo | (hi << 16);
        }
        uint4v w0 = {w[0], w[1], w[2], w[3]};
        uint4v w1 = {w[4], w[5], w[6], w[7]};
        *(uint4v*)(dst)     = w0;
        *(uint4v*)(dst + 8) = w1;
    }
    // partial sum of squares over this block's 64 channels (fp32, exact)
    {
        int n  = t & 63;
        int cq = t >> 6;
        float ss = 0.f;
        #pragma unroll
        for (int i = 0; i < 16; ++i) {
            float v = tile[cq * 16 + i][n];
            ss = fmaf(v, v, ss);
        }
        red[cq][n] = ss;
    }
    __syncthreads();
    if (t < 64) {
        float s = red[0][t] + red[1][t] + red[2][t] + red[3][t];
        psum[((size_t)(b * 64 + nc) * 64 + t) * 4 + cc] = s;
    }
}

// ---------------------------------------------------------------------------
// k_inv: invn[i] = 1/max(sqrt(sum_cc psum), 1e-8). grid 64 x 256.
// ---------------------------------------------------------------------------
__global__ __launch_bounds__(256) void k_inv(const float* __restrict__ psum,
                                             float* __restrict__ invn) {
    int i = blockIdx.x * 256 + threadIdx.x;   // 0..16383
    floatx4 p = *(const floatx4*)(psum + (size_t)i * 4);
    float ss = (p[0] + p[1]) + (p[2] + p[3]);
    invn[i] = 1.f / fmaxf(sqrtf(ss), 1e-8f);
}

// ---------------------------------------------------------------------------
// k_conv: tf[b][o][n] = bf16( sum_c W[o][c]*x[b][c][n] + bias[o] )
// grid 1024 (b*4ot*64nt) x 256 thr (4 waves).
// ---------------------------------------------------------------------------
__global__ __launch_bounds__(256) void k_conv(const float* __restrict__ Wm,
                                              const float* __restrict__ bias,
                                              const unsigned short* __restrict__ xT,
                                              unsigned short* __restrict__ tf) {
    int blk = blockIdx.x;
    int b  = blk >> 8;
    int ot = (blk >> 6) & 3;
    int nt = blk & 63;
    int o0 = ot << 6, n0 = nt << 6;
    int t = threadIdx.x;
    int w = t >> 6, l = t & 63, l15 = l & 15, q = l >> 4;
    int orow = o0 + 16 * w + l15;

    floatx4 zero4 = {0.f, 0.f, 0.f, 0.f};
    floatx4 acc[4] = {zero4, zero4, zero4, zero4};
    const float* wp0 = Wm + (size_t)orow * CC + q * 8;

    #pragma unroll
    for (int kk = 0; kk < 8; ++kk) {
        const float* wp = wp0 + kk * 32;
        floatx4 wa = *(const floatx4*)wp;
        floatx4 wb = *(const floatx4*)(wp + 4);
        short8 af;
        #pragma unroll
        for (int j = 0; j < 4; ++j) {
            af[j]     = (short)f2bf(wa[j]);
            af[4 + j] = (short)f2bf(wb[j]);
        }
        #pragma unroll
        for (int s = 0; s < 4; ++s) {
            const unsigned short* bp =
                xT + (size_t)(b * NN + n0 + 16 * s + l15) * CC + kk * 32 + q * 8;
            short8 bf = *(const short8*)bp;
            acc[s] = mfma16(af, bf, acc[s]);
        }
    }
    int obase = o0 + 16 * w + q * 4;    // D rows = quad*4 + i
    float bv0 = bias[obase + 0], bv1 = bias[obase + 1];
    float bv2 = bias[obase + 2], bv3 = bias[obase + 3];
    #pragma unroll
    for (int s = 0; s < 4; ++s) {
        int n = n0 + 16 * s + l15;      // D col = lane&15
        tf[(size_t)(b * CC + obase + 0) * NN + n] = f2bf(acc[s][0] + bv0);
        tf[(size_t)(b * CC + obase + 1) * NN + n] = f2bf(acc[s][1] + bv1);
        tf[(size_t)(b * CC + obase + 2) * NN + n] = f2bf(acc[s][2] + bv2);
        tf[(size_t)(b * CC + obase + 3) * NN + n] = f2bf(acc[s][3] + bv3);
    }
}

// ---------------------------------------------------------------------------
// k_fused v2: Q-tile 32, 256 thr (4 waves), grid 512 (2 blocks/CU).
// No xm staging (S B-frags straight from L2). Double-buffered pbuf ->
// ONE barrier per key-tile, and that barrier only drains lgkmcnt (inline
// asm), so global prefetches stay in flight across it.
// Wave wv: S: mk-subtile ms=wv, both nq-subtiles. GEMM2: c-tiles 4*wv..+3.
// ---------------------------------------------------------------------------
__global__ __launch_bounds__(256, 2) void k_fused(
        const unsigned short* __restrict__ xT,   // [B][N][C] bf16
        const unsigned short* __restrict__ tf,   // [B][C][N] bf16
        const float* __restrict__ invn,          // [B][N]
        float* __restrict__ out) {               // [B][C][N] f32
    int blk = blockIdx.x;           // b*128 + qtile
    int b  = blk >> 7;
    int n0 = (blk & 127) << 5;
    int t  = threadIdx.x;
    int wv = t >> 6;
    int l15 = t & 15, q = (t & 63) >> 4;
    int ms = wv;                    // S-phase mk-subtile
    int cg = wv;                    // GEMM2 c-group

    __shared__ unsigned short pbuf[2][2][16 * 72];   // [buf][nq-sub][16 nq][72 m]

    const unsigned short* xTb = xT + (size_t)b * NN * CC;
    const unsigned short* tfb = tf + (size_t)b * CC * NN;
    const float* invb = invn + b * NN;

    // persistent Xq A-fragments: A[m=lane&15][k=quad*8+j]
    short8 aq[2][8];
    #pragma unroll
    for (int s = 0; s < 2; ++s) {
        const unsigned short* p = xTb + (size_t)(n0 + 16 * s + l15) * CC + q * 8;
        #pragma unroll
        for (int kk = 0; kk < 8; ++kk) aq[s][kk] = *(const short8*)(p + kk * 32);
    }
    float invq[2][4];
    #pragma unroll
    for (int s = 0; s < 2; ++s)
        #pragma unroll
        for (int i = 0; i < 4; ++i)
            invq[s][i] = invb[n0 + 16 * s + q * 4 + i];

    floatx4 zero4 = {0.f, 0.f, 0.f, 0.f};
    floatx4 oacc[2][4];
    #pragma unroll
    for (int s = 0; s < 2; ++s)
        #pragma unroll
        for (int ct = 0; ct < 4; ++ct) oacc[s][ct] = zero4;

    // ping-pong S B-fragment registers; preload tile 0
    short8 bq0[8], bq1[8];
    {
        const unsigned short* bs = xTb + (size_t)(16 * ms + l15) * CC + q * 8;
        #pragma unroll
        for (int kk = 0; kk < 8; ++kk) bq0[kk] = *(const short8*)(bs + kk * 32);
    }

    auto step = [&](int it, short8* bqc, short8* bqn, int B) {
        int m0 = it << 6;
        // oldest-first issue order: invm, tf frags, then next-tile prefetch
        float invm = invb[m0 + 16 * ms + l15];
        short8 tfr[2][4];
        #pragma unroll
        for (int kk2 = 0; kk2 < 2; ++kk2)
            #pragma unroll
            for (int ct = 0; ct < 4; ++ct) {
                int c = 16 * (4 * cg + ct) + l15;
                tfr[kk2][ct] = *(const short8*)(tfb + (size_t)c * NN + m0 + kk2 * 32 + q * 8);
            }
        {   // prefetch next key tile's B-frags (consumed next step)
            int mN = (it < 63) ? (m0 + 64) : m0;
            const unsigned short* bs = xTb + (size_t)(mN + 16 * ms + l15) * CC + q * 8;
            #pragma unroll
            for (int kk = 0; kk < 8; ++kk) bqn[kk] = *(const short8*)(bs + kk * 32);
        }
        // ---- S = Xq^T Xm, parity-split chains ----
        floatx4 s0a = zero4, s0b = zero4, s1a = zero4, s1b = zero4;
        #pragma unroll
        for (int kk = 0; kk < 8; kk += 2) {
            s0a = mfma16(aq[0][kk],     bqc[kk],     s0a);
            s1a = mfma16(aq[1][kk],     bqc[kk],     s1a);
            s0b = mfma16(aq[0][kk + 1], bqc[kk + 1], s0b);
            s1b = mfma16(aq[1][kk + 1], bqc[kk + 1], s1b);
        }
        // ---- P = relu(S*invq*invm)^2 -> bf16 -> pbuf[B] ----
        #pragma unroll
        for (int s = 0; s < 2; ++s) {
            floatx4 sv = (s == 0) ? (s0a + s0b) : (s1a + s1b);
            unsigned short* pw = &pbuf[B][s][16 * ms + l15];
            #pragma unroll
            for (int i = 0; i < 4; ++i) {
                float v = sv[i] * (invq[s][i] * invm);
                v = fmaxf(v, 0.f);
                v = v * v;
                pw[(q * 4 + i) * 72] = f2bf(v);
            }
        }
        // barrier draining ONLY LDS ops; global prefetches stay in flight
        asm volatile("s_waitcnt lgkmcnt(0)\n\ts_barrier" ::: "memory");
        // ---- O[c][nq] += tf * P ----
        #pragma unroll
        for (int kk2 = 0; kk2 < 2; ++kk2) {
            short8 pb0 = *(const short8*)(&pbuf[B][0][l15 * 72 + kk2 * 32 + q * 8]);
            short8 pb1 = *(const short8*)(&pbuf[B][1][l15 * 72 + kk2 * 32 + q * 8]);
            #pragma unroll
            for (int ct = 0; ct < 4; ++ct) {
                oacc[0][ct] = mfma16(tfr[kk2][ct], pb0, oacc[0][ct]);
                oacc[1][ct] = mfma16(tfr[kk2][ct], pb1, oacc[1][ct]);
            }
        }
    };

    for (int it = 0; it < 64; it += 2) {
        step(it,     bq0, bq1, 0);
        step(it + 1, bq1, bq0, 1);
    }

    // epilogue: D row = c_local (quad*4+i), D col = nq (lane&15) -> coalesced
    float* ob = out + (size_t)b * CC * NN;
    #pragma unroll
    for (int s = 0; s < 2; ++s)
        #pragma unroll
        for (int ct = 0; ct < 4; ++ct)
            #pragma unroll
            for (int i = 0; i < 4; ++i) {
                int c = 16 * (4 * cg + ct) + q * 4 + i;
                ob[(size_t)c * NN + n0 + 16 * s + l15] = oacc[s][ct][i];
            }
}

// ---------------------------------------------------------------------------
extern "C" void kernel_launch(void* const* d_in, const int* in_sizes, int n_in,
                              void* d_out, int out_size, void* d_ws, size_t ws_size,
                              hipStream_t stream) {
    const float* x    = (const float*)d_in[0];   // [4,256,64,64]
    const float* Wm   = (const float*)d_in[1];   // [256,256]
    const float* bias = (const float*)d_in[2];   // [256]
    float* out = (float*)d_out;

    // ws: psum 256KB | invn 64KB | xT bf16 8MB | tf bf16 8MB
    char* ws = (char*)d_ws;
    float* psum        = (float*)ws;
    float* invn        = (float*)(ws + 262144);
    unsigned short* xT = (unsigned short*)(ws + 262144 + 65536);
    unsigned short* tf = (unsigned short*)(ws + 262144 + 65536 + 8388608);

    k_trans<<<1024, 256, 0, stream>>>(x, xT, psum);
    k_inv  <<<64,   256, 0, stream>>>(psum, invn);
    k_conv <<<1024, 256, 0, stream>>>(Wm, bias, xT, tf);
    k_fused<<<512,  256, 0, stream>>>(xT, tf, invn, out);
}

// Round 3
// 174.029 us; speedup vs baseline: 1.9090x; 1.9090x over previous
//
#include <hip/hip_runtime.h>
#include <stdint.h>

#define CC 256
#define NN 4096   // H*W = 64*64

typedef __attribute__((ext_vector_type(8))) short short8;
typedef __attribute__((ext_vector_type(4))) float floatx4;
typedef __attribute__((ext_vector_type(4))) unsigned int uint4v;
typedef __attribute__((ext_vector_type(2))) unsigned int uint2v;

__device__ __forceinline__ unsigned short f2bf(float f) {
    unsigned int u = __builtin_bit_cast(unsigned int, f);
    u = (u + 0x7FFFu + ((u >> 16) & 1u)) >> 16;   // RNE
    return (unsigned short)u;
}

__device__ __forceinline__ floatx4 mfma16(short8 a, short8 b, floatx4 c) {
    return __builtin_amdgcn_mfma_f32_16x16x32_bf16(a, b, c, 0, 0, 0);
}

// swizzled LDS offset (shorts): row-major 64x256, 16B granule g XOR'd by row&7
// -> both staging ds_write_b128 and fragment ds_read_b128 are ~conflict-free.
__device__ __forceinline__ int swz8(int row, int g) {
    return row * 256 + (((g ^ (row & 7)) & 31) << 3);
}

// ---------------------------------------------------------------------------
// k_wcast: W fp32 -> bf16 (once; removes per-block cvt from k_conv)
// ---------------------------------------------------------------------------
__global__ __launch_bounds__(256) void k_wcast(const float* __restrict__ Wm,
                                               unsigned short* __restrict__ wbf) {
    int i = blockIdx.x * 256 + threadIdx.x;      // 0..16383 (x4 floats)
    floatx4 v = *(const floatx4*)(Wm + (size_t)i * 4);
    unsigned int a = f2bf(v[0]) | ((unsigned int)f2bf(v[1]) << 16);
    unsigned int b = f2bf(v[2]) | ((unsigned int)f2bf(v[3]) << 16);
    uint2v p = {a, b};
    *(uint2v*)(wbf + (size_t)i * 4) = p;
}

// ---------------------------------------------------------------------------
// k_trans: xT[b][n][c] = bf16(x[b][c][n])  + partial norms psum
// ---------------------------------------------------------------------------
__global__ __launch_bounds__(256) void k_trans(const float* __restrict__ x,
                                               unsigned short* __restrict__ xT,
                                               float* __restrict__ psum) {
    int blk = blockIdx.x;
    int b  = blk >> 8;
    int cc = (blk >> 6) & 3;
    int nc = blk & 63;
    int c0 = cc << 6, n0 = nc << 6;
    __shared__ float tile[64][65];
    __shared__ float red[4][64];
    int t = threadIdx.x;
    {
        int c   = t >> 2;
        int nn4 = (t & 3) << 4;
        const float* src = x + (size_t)(b * CC + c0 + c) * NN + n0 + nn4;
        #pragma unroll
        for (int j = 0; j < 16; j += 4) {
            floatx4 v = *(const floatx4*)(src + j);
            tile[c][nn4 + j + 0] = v[0];
            tile[c][nn4 + j + 1] = v[1];
            tile[c][nn4 + j + 2] = v[2];
            tile[c][nn4 + j + 3] = v[3];
        }
    }
    __syncthreads();
    {
        int n  = t >> 2;
        int ci = (t & 3) << 4;
        unsigned short* dst = xT + (size_t)(b * NN + n0 + n) * CC + c0 + ci;
        unsigned int w[8];
        #pragma unroll
        for (int j = 0; j < 8; ++j) {
            unsigned int lo = f2bf(tile[ci + 2 * j][n]);
            unsigned int hi = f2bf(tile[ci + 2 * j + 1][n]);
            w[j] = lo | (hi << 16);
        }
        uint4v w0 = {w[0], w[1], w[2], w[3]};
        uint4v w1 = {w[4], w[5], w[6], w[7]};
        *(uint4v*)(dst)     = w0;
        *(uint4v*)(dst + 8) = w1;
    }
    {
        int n  = t & 63;
        int cq = t >> 6;
        float ss = 0.f;
        #pragma unroll
        for (int i = 0; i < 16; ++i) {
            float v = tile[cq * 16 + i][n];
            ss = fmaf(v, v, ss);
        }
        red[cq][n] = ss;
    }
    __syncthreads();
    if (t < 64) {
        float s = red[0][t] + red[1][t] + red[2][t] + red[3][t];
        psum[((size_t)(b * 64 + nc) * 64 + t) * 4 + cc] = s;
    }
}

// ---------------------------------------------------------------------------
// k_inv
// ---------------------------------------------------------------------------
__global__ __launch_bounds__(256) void k_inv(const float* __restrict__ psum,
                                             float* __restrict__ invn) {
    int i = blockIdx.x * 256 + threadIdx.x;
    floatx4 p = *(const floatx4*)(psum + (size_t)i * 4);
    float ss = (p[0] + p[1]) + (p[2] + p[3]);
    invn[i] = 1.f / fmaxf(sqrtf(ss), 1e-8f);
}

// ---------------------------------------------------------------------------
// k_conv: tf = W*x + b, output written in MFMA-A-fragment order (tfF) so
// k_fused's 2nd-GEMM A-loads are perfectly coalesced lane*16B reads.
// tfF[b][mt(64)][ct(16)][kk2(2)][lane(64)][j(8)] shorts; value at
// (c = 16*ct + (lane&15), m = mt*64 + kk2*32 + (lane>>4)*8 + j).
// Block = (b, n-tile 64): stage xT tile to swizzled LDS once, 4 waves x
// (64 o-rows each) -> 512 MFMA/block.
// ---------------------------------------------------------------------------
__global__ __launch_bounds__(256) void k_conv(const unsigned short* __restrict__ wbf,
                                              const float* __restrict__ bias,
                                              const unsigned short* __restrict__ xT,
                                              unsigned short* __restrict__ tfF) {
    int blk = blockIdx.x;             // b*64 + nt
    int b = blk >> 6, nt = blk & 63;
    int n0 = nt << 6;
    int t = threadIdx.x;
    int w = t >> 6, l15 = t & 15, q = (t & 63) >> 4;

    __shared__ unsigned short xm[64 * 256];
    const unsigned short* xTb = xT + (size_t)b * NN * CC;

    #pragma unroll
    for (int j = 0; j < 8; ++j) {
        int grow = j * 8 + (t >> 5);
        int g = t & 31;
        uint4v v = *(const uint4v*)(xTb + (size_t)(n0 + grow) * CC + g * 8);
        *(uint4v*)(xm + swz8(grow, g)) = v;
    }
    __syncthreads();

    floatx4 zero4 = {0.f, 0.f, 0.f, 0.f};
    floatx4 acc[4][4];                 // [ot][ns]
    #pragma unroll
    for (int ot = 0; ot < 4; ++ot)
        #pragma unroll
        for (int ns = 0; ns < 4; ++ns) acc[ot][ns] = zero4;

    #pragma unroll
    for (int kk = 0; kk < 8; ++kk) {
        short8 aw[4], bx[4];
        #pragma unroll
        for (int ot = 0; ot < 4; ++ot)
            aw[ot] = *(const short8*)(wbf + (size_t)(64 * w + 16 * ot + l15) * CC + kk * 32 + q * 8);
        #pragma unroll
        for (int ns = 0; ns < 4; ++ns)
            bx[ns] = *(const short8*)(xm + swz8(16 * ns + l15, kk * 4 + q));
        #pragma unroll
        for (int ot = 0; ot < 4; ++ot)
            #pragma unroll
            for (int ns = 0; ns < 4; ++ns)
                acc[ot][ns] = mfma16(aw[ot], bx[ns], acc[ot][ns]);
    }

    unsigned short* dst = tfF + (size_t)(b * 64 + nt) * 16 * 1024;
    #pragma unroll
    for (int ot = 0; ot < 4; ++ot) {
        int ct = 4 * w + ot;
        float bv[4];
        #pragma unroll
        for (int i = 0; i < 4; ++i) bv[i] = bias[16 * ct + q * 4 + i];
        #pragma unroll
        for (int ns = 0; ns < 4; ++ns)
            #pragma unroll
            for (int i = 0; i < 4; ++i) {
                int mloc = 16 * ns + l15;
                int kk2 = mloc >> 5, qp = (mloc >> 3) & 3, j = mloc & 7;
                int lanep = qp * 16 + (q * 4 + i);
                dst[ct * 1024 + kk2 * 512 + lanep * 8 + j] = f2bf(acc[ot][ns][i] + bv[i]);
            }
    }
}

// ---------------------------------------------------------------------------
// k_fused v3: Q=64, m-tile 64, 512 thr (8 waves), grid 256.
// Hot loop: staging loads coalesced 1KB/wave -> swizzled single-buffer xm;
// tf A-frags coalesced from tfF; TWO lgkm-only barriers/step, NO vmcnt
// drain in the loop (stage regs carry loads across both barriers).
// Wave wv: S: ms=wv&3, nq pair {2np,2np+1} (np=wv>>2), aq persistent.
//          G2: c-tiles {wv, wv+8} x all 4 nq.
// ---------------------------------------------------------------------------
__global__ __launch_bounds__(512, 2) void k_fused(
        const unsigned short* __restrict__ xT,    // [B][N][C] bf16
        const unsigned short* __restrict__ tfF,   // fragment-ordered
        const float* __restrict__ invn,           // [B][N]
        float* __restrict__ out) {                // [B][C][N] f32
    int blk = blockIdx.x;            // b*64 + qtile
    int b  = blk >> 6;
    int n0 = (blk & 63) << 6;
    int t  = threadIdx.x;
    int wv = t >> 6;
    int l15 = t & 15, q = (t & 63) >> 4;
    int ms = wv & 3;
    int np = wv >> 2;                // nq pair {2np, 2np+1}

    __shared__ unsigned short xm[64 * 256];       // swizzled, single-buffered
    __shared__ unsigned short pbuf[4][16 * 72];   // padded (72): 2-way reads

    const unsigned short* xTb = xT + (size_t)b * NN * CC;
    const unsigned short* tFb = tfF + (size_t)b * 64 * 16 * 1024;
    const float* invb = invn + b * NN;

    // persistent Xq A-frags: A[m=lane&15][k=quad*8+j]
    short8 aq[2][8];
    #pragma unroll
    for (int s = 0; s < 2; ++s) {
        const unsigned short* p = xTb + (size_t)(n0 + 16 * (2 * np + s) + l15) * CC + q * 8;
        #pragma unroll
        for (int kk = 0; kk < 8; ++kk) aq[s][kk] = *(const short8*)(p + kk * 32);
    }
    float invq[2][4];
    #pragma unroll
    for (int s = 0; s < 2; ++s)
        #pragma unroll
        for (int i = 0; i < 4; ++i)
            invq[s][i] = invb[n0 + 16 * (2 * np + s) + q * 4 + i];

    floatx4 zero4 = {0.f, 0.f, 0.f, 0.f};
    floatx4 oacc[2][4];              // [ct-half][nqs]
    #pragma unroll
    for (int ci = 0; ci < 2; ++ci)
        #pragma unroll
        for (int nqs = 0; nqs < 4; ++nqs) oacc[ci][nqs] = zero4;

    // staging map: pass j -> row j*16 + t/32, granule t&31 (coalesced global)
    int srow = t >> 5;
    int sg   = t & 31;

    uint4v gx[4];
    // prologue: stage tile 0
    #pragma unroll
    for (int j = 0; j < 4; ++j)
        gx[j] = *(const uint4v*)(xTb + (size_t)(j * 16 + srow) * CC + sg * 8);
    #pragma unroll
    for (int j = 0; j < 4; ++j)
        *(uint4v*)(xm + swz8(j * 16 + srow, sg)) = gx[j];
    __syncthreads();

    for (int it = 0; it < 64; ++it) {
        int m0 = it << 6;
        // ---- issue next-tile staging loads (consumed after G2) ----
        int m1 = (it < 63 ? (it + 1) : 63) << 6;
        #pragma unroll
        for (int j = 0; j < 4; ++j)
            gx[j] = *(const uint4v*)(xTb + (size_t)(m1 + j * 16 + srow) * CC + sg * 8);
        // ---- issue tf A-frag loads for this tile (coalesced) ----
        short8 tfr[2][2];            // [kk2][ct-half]
        #pragma unroll
        for (int kk2 = 0; kk2 < 2; ++kk2)
            #pragma unroll
            for (int ci = 0; ci < 2; ++ci) {
                int ct = wv + 8 * ci;
                tfr[kk2][ci] = *(const short8*)(tFb + (size_t)(it * 16 + ct) * 1024
                                                + kk2 * 512 + (t & 63) * 8);
            }
        float invm = invb[m0 + 16 * ms + l15];

        // ---- S = Xq^T Xm from swizzled LDS ----
        short8 bq[8];
        #pragma unroll
        for (int kk = 0; kk < 8; ++kk)
            bq[kk] = *(const short8*)(xm + swz8(16 * ms + l15, kk * 4 + q));
        floatx4 s0a = zero4, s0b = zero4, s1a = zero4, s1b = zero4;
        #pragma unroll
        for (int kk = 0; kk < 8; kk += 2) {
            s0a = mfma16(aq[0][kk],     bq[kk],     s0a);
            s1a = mfma16(aq[1][kk],     bq[kk],     s1a);
            s0b = mfma16(aq[0][kk + 1], bq[kk + 1], s0b);
            s1b = mfma16(aq[1][kk + 1], bq[kk + 1], s1b);
        }
        // ---- P = relu(S*invq*invm)^2 -> pbuf ----
        #pragma unroll
        for (int s = 0; s < 2; ++s) {
            floatx4 sv = (s == 0) ? (s0a + s0b) : (s1a + s1b);
            unsigned short* pw = &pbuf[2 * np + s][16 * ms + l15];
            #pragma unroll
            for (int i = 0; i < 4; ++i) {
                float v = sv[i] * (invq[s][i] * invm);
                v = fmaxf(v, 0.f);
                v = v * v;
                pw[(q * 4 + i) * 72] = f2bf(v);
            }
        }
        // bar1: P visible + all xm reads of this tile done (lgkm only)
        asm volatile("s_waitcnt lgkmcnt(0)\n\ts_barrier" ::: "memory");

        // ---- O[c][nq] += tf * P ----
        #pragma unroll
        for (int kk2 = 0; kk2 < 2; ++kk2) {
            #pragma unroll
            for (int nqs = 0; nqs < 4; ++nqs) {
                short8 pb = *(const short8*)(&pbuf[nqs][l15 * 72 + kk2 * 32 + q * 8]);
                oacc[0][nqs] = mfma16(tfr[kk2][0], pb, oacc[0][nqs]);
                oacc[1][nqs] = mfma16(tfr[kk2][1], pb, oacc[1][nqs]);
            }
        }
        // ---- write next tile into xm (reg dep waits vmcnt for gx only) ----
        #pragma unroll
        for (int j = 0; j < 4; ++j)
            *(uint4v*)(xm + swz8(j * 16 + srow, sg)) = gx[j];
        // bar2: next tile visible (lgkm only)
        asm volatile("s_waitcnt lgkmcnt(0)\n\ts_barrier" ::: "memory");
    }

    // epilogue: D row = c-local (q*4+i), col = nq (l15) -> coalesced stores
    float* ob = out + (size_t)b * CC * NN;
    #pragma unroll
    for (int ci = 0; ci < 2; ++ci) {
        int ct = wv + 8 * ci;
        #pragma unroll
        for (int nqs = 0; nqs < 4; ++nqs)
            #pragma unroll
            for (int i = 0; i < 4; ++i) {
                int c = 16 * ct + q * 4 + i;
                ob[(size_t)c * NN + n0 + 16 * nqs + l15] = oacc[ci][nqs][i];
            }
    }
}

// ---------------------------------------------------------------------------
extern "C" void kernel_launch(void* const* d_in, const int* in_sizes, int n_in,
                              void* d_out, int out_size, void* d_ws, size_t ws_size,
                              hipStream_t stream) {
    const float* x    = (const float*)d_in[0];   // [4,256,64,64]
    const float* Wm   = (const float*)d_in[1];   // [256,256]
    const float* bias = (const float*)d_in[2];   // [256]
    float* out = (float*)d_out;

    // ws: psum 256KB | invn 64KB | xT 8MB | wbf 128KB | tfF 8MB  (~16.8MB)
    char* ws = (char*)d_ws;
    float* psum         = (float*)ws;
    float* invn         = (float*)(ws + 262144);
    unsigned short* xT  = (unsigned short*)(ws + 262144 + 65536);
    unsigned short* wbf = (unsigned short*)(ws + 262144 + 65536 + 8388608);
    unsigned short* tfF = (unsigned short*)(ws + 262144 + 65536 + 8388608 + 131072);

    k_wcast<<<64,   256, 0, stream>>>(Wm, wbf);
    k_trans<<<1024, 256, 0, stream>>>(x, xT, psum);
    k_inv  <<<64,   256, 0, stream>>>(psum, invn);
    k_conv <<<256,  256, 0, stream>>>(wbf, bias, xT, tfF);
    k_fused<<<256,  512, 0, stream>>>(xT, tfF, invn, out);
}

// Round 6
// 169.859 us; speedup vs baseline: 1.9559x; 1.0245x over previous
//
#include <hip/hip_runtime.h>
#include <stdint.h>

#define CC 256
#define NN 4096   // H*W = 64*64

typedef __attribute__((ext_vector_type(8))) short short8;
typedef __attribute__((ext_vector_type(4))) float floatx4;
typedef __attribute__((ext_vector_type(4))) unsigned int uint4v;
typedef __attribute__((ext_vector_type(2))) unsigned int uint2v;

__device__ __forceinline__ unsigned short f2bf(float f) {
    unsigned int u = __builtin_bit_cast(unsigned int, f);
    u = (u + 0x7FFFu + ((u >> 16) & 1u)) >> 16;   // RNE
    return (unsigned short)u;
}

__device__ __forceinline__ floatx4 mfma16(short8 a, short8 b, floatx4 c) {
    return __builtin_amdgcn_mfma_f32_16x16x32_bf16(a, b, c, 0, 0, 0);
}

// swizzled LDS offset (shorts): row-major 64x256, 16B granule g XOR'd by row&7
__device__ __forceinline__ int swz8(int row, int g) {
    return row * 256 + (((g ^ (row & 7)) & 31) << 3);
}

// ---------------------------------------------------------------------------
// k_wcast: W fp32 -> wF bf16 A-fragment order.
// wF[f = ct*8+kk][lane*8+j] = W[16ct + (lane&15)][32kk + (lane>>4)*8 + j]
// ---------------------------------------------------------------------------
__global__ __launch_bounds__(256) void k_wcast(const float* __restrict__ Wm,
                                               unsigned short* __restrict__ wF) {
    int idx = blockIdx.x * 256 + threadIdx.x;   // 0..8191
    int f = idx >> 6, lane = idx & 63;
    int ct = f >> 3, kk = f & 7;
    int l15 = lane & 15, q = lane >> 4;
    const float* src = Wm + (size_t)(16 * ct + l15) * CC + 32 * kk + 8 * q;
    floatx4 a = *(const floatx4*)src;
    floatx4 c = *(const floatx4*)(src + 4);
    unsigned int w0 = f2bf(a[0]) | ((unsigned int)f2bf(a[1]) << 16);
    unsigned int w1 = f2bf(a[2]) | ((unsigned int)f2bf(a[3]) << 16);
    unsigned int w2 = f2bf(c[0]) | ((unsigned int)f2bf(c[1]) << 16);
    unsigned int w3 = f2bf(c[2]) | ((unsigned int)f2bf(c[3]) << 16);
    uint4v p = {w0, w1, w2, w3};
    *(uint4v*)(wF + (size_t)f * 512 + lane * 8) = p;
}

// ---------------------------------------------------------------------------
// k_trans (R3-proven): xT[b][n][c] = bf16(x[b][c][n]) + partial norms psum
// ---------------------------------------------------------------------------
__global__ __launch_bounds__(256) void k_trans(const float* __restrict__ x,
                                               unsigned short* __restrict__ xT,
                                               float* __restrict__ psum) {
    int blk = blockIdx.x;
    int b  = blk >> 8;
    int cc = (blk >> 6) & 3;
    int nc = blk & 63;
    int c0 = cc << 6, n0 = nc << 6;
    __shared__ float tile[64][65];
    __shared__ float red[4][64];
    int t = threadIdx.x;
    {
        int c   = t >> 2;
        int nn4 = (t & 3) << 4;
        const float* src = x + (size_t)(b * CC + c0 + c) * NN + n0 + nn4;
        #pragma unroll
        for (int j = 0; j < 16; j += 4) {
            floatx4 v = *(const floatx4*)(src + j);
            tile[c][nn4 + j + 0] = v[0];
            tile[c][nn4 + j + 1] = v[1];
            tile[c][nn4 + j + 2] = v[2];
            tile[c][nn4 + j + 3] = v[3];
        }
    }
    __syncthreads();
    {
        int n  = t >> 2;
        int ci = (t & 3) << 4;
        unsigned short* dst = xT + (size_t)(b * NN + n0 + n) * CC + c0 + ci;
        unsigned int w[8];
        #pragma unroll
        for (int j = 0; j < 8; ++j) {
            unsigned int lo = f2bf(tile[ci + 2 * j][n]);
            unsigned int hi = f2bf(tile[ci + 2 * j + 1][n]);
            w[j] = lo | (hi << 16);
        }
        uint4v w0 = {w[0], w[1], w[2], w[3]};
        uint4v w1 = {w[4], w[5], w[6], w[7]};
        *(uint4v*)(dst)     = w0;
        *(uint4v*)(dst + 8) = w1;
    }
    {
        int n  = t & 63;
        int cq = t >> 6;
        float ss = 0.f;
        #pragma unroll
        for (int i = 0; i < 16; ++i) {
            float v = tile[cq * 16 + i][n];
            ss = fmaf(v, v, ss);
        }
        red[cq][n] = ss;
    }
    __syncthreads();
    if (t < 64) {
        float s = red[0][t] + red[1][t] + red[2][t] + red[3][t];
        psum[((size_t)(b * 64 + nc) * 64 + t) * 4 + cc] = s;
    }
}

// ---------------------------------------------------------------------------
// k_inv
// ---------------------------------------------------------------------------
__global__ __launch_bounds__(256) void k_inv(const float* __restrict__ psum,
                                             float* __restrict__ invn) {
    int i = blockIdx.x * 256 + threadIdx.x;
    floatx4 p = *(const floatx4*)(psum + (size_t)i * 4);
    float ss = (p[0] + p[1]) + (p[2] + p[3]);
    invn[i] = 1.f / fmaxf(sqrtf(ss), 1e-8f);
}

// ---------------------------------------------------------------------------
// k_gfrag: xT -> xG in EXACTLY R3's tfF layout (proven read pattern):
// xG[b][mt(64)][cct(16)][kk2(2)][lane(64)][j(8)] =
//   X[c = 16cct + (lane&15)][m = 64mt + 32kk2 + (lane>>4)*8 + j]
// grid 256 (b*64+mt) x 256 thr.
// ---------------------------------------------------------------------------
__global__ __launch_bounds__(256) void k_gfrag(const unsigned short* __restrict__ xT,
                                               unsigned short* __restrict__ xG) {
    int blk = blockIdx.x;
    int b = blk >> 6, mt = blk & 63;
    __shared__ unsigned short tile[64 * 264];     // [m-local][c], stride 264
    int t = threadIdx.x;
    const unsigned short* src = xT + (size_t)(b * NN + mt * 64) * CC;
    #pragma unroll
    for (int j = 0; j < 8; ++j) {
        int idx = j * 256 + t;                    // 0..2047
        int row = idx >> 5, g = idx & 31;
        uint4v v = *(const uint4v*)(src + (size_t)row * CC + g * 8);
        *(uint4v*)(tile + row * 264 + g * 8) = v;
    }
    __syncthreads();
    unsigned short* dst = xG + (size_t)(b * 64 + mt) * 16 * 1024;
    int lane = t & 63, l15 = lane & 15, q = lane >> 4;
    #pragma unroll
    for (int cc2 = 0; cc2 < 4; ++cc2) {
        int cct = (t >> 6) * 4 + cc2;
        #pragma unroll
        for (int kk2 = 0; kk2 < 2; ++kk2) {
            unsigned int w[4];
            #pragma unroll
            for (int j2 = 0; j2 < 4; ++j2) {
                unsigned int lo = tile[(32 * kk2 + 8 * q + 2 * j2) * 264 + 16 * cct + l15];
                unsigned int hi = tile[(32 * kk2 + 8 * q + 2 * j2 + 1) * 264 + 16 * cct + l15];
                w[j2] = lo | (hi << 16);
            }
            uint4v p = {w[0], w[1], w[2], w[3]};
            *(uint4v*)(dst + cct * 1024 + kk2 * 512 + lane * 8) = p;
        }
    }
}

// ---------------------------------------------------------------------------
// k_fused v5: R3-proven loop + reassociation out = W*(X*P) + b*colsum(P).
// Loop (verbatim R3): xm swizzled staging, S = A(xq)*B(xm-LDS), scalar P
// writes, 2 lgkm-only barriers. Changed vs R3: G2 A-operand = xG (was tfF),
// Zacc kept in regs; colsum via per-lane f32 adds + shfl reduce (no MFMA).
// Epilogue: Z->zbuf (DEDICATED LDS, scalar stores), O = W*Z + b*svals.
// ---------------------------------------------------------------------------
__global__ __launch_bounds__(512, 2) void k_fused(
        const unsigned short* __restrict__ xT,    // [B][N][C] bf16
        const unsigned short* __restrict__ xG,    // fragment-ordered
        const unsigned short* __restrict__ wF,    // W A-frags
        const float* __restrict__ bias,
        const float* __restrict__ invn,           // [B][N]
        float* __restrict__ out) {                // [B][C][N] f32
    int blk = blockIdx.x;            // b*64 + qtile
    int b  = blk >> 6;
    int n0 = (blk & 63) << 6;
    int t  = threadIdx.x;
    int wv = t >> 6;
    int l15 = t & 15, q = (t & 63) >> 4;
    int ms = wv & 3;
    int np = wv >> 2;                // nq pair {2np, 2np+1}

    __shared__ unsigned short xm[64 * 256];       // swizzled staging
    __shared__ unsigned short pbuf[4][16 * 72];   // P round-trip
    __shared__ unsigned short zbuf[64 * 264];     // DEDICATED (no alias)
    __shared__ float spbuf2[4][64];               // colsum partials [ms][nq]

    const unsigned short* xTb = xT + (size_t)b * NN * CC;
    const unsigned short* xGb = xG + (size_t)b * 64 * 16 * 1024;
    const float* invb = invn + b * NN;

    // persistent Xq A-frags (R3 proven): A[nq=lane&15][k=c]
    short8 aq[2][8];
    #pragma unroll
    for (int s = 0; s < 2; ++s) {
        const unsigned short* p = xTb + (size_t)(n0 + 16 * (2 * np + s) + l15) * CC + q * 8;
        #pragma unroll
        for (int kk = 0; kk < 8; ++kk) aq[s][kk] = *(const short8*)(p + kk * 32);
    }
    float invq[2][4];
    #pragma unroll
    for (int s = 0; s < 2; ++s)
        #pragma unroll
        for (int i = 0; i < 4; ++i)
            invq[s][i] = invb[n0 + 16 * (2 * np + s) + q * 4 + i];

    floatx4 zero4 = {0.f, 0.f, 0.f, 0.f};
    floatx4 Zacc[2][4];              // [ci: cct=wv+8ci][nqs]
    #pragma unroll
    for (int ci = 0; ci < 2; ++ci)
        #pragma unroll
        for (int nqs = 0; nqs < 4; ++nqs) Zacc[ci][nqs] = zero4;
    float csum[2][4];                // colsum partials (rows 16*(2np+s)+4q+i)
    #pragma unroll
    for (int s = 0; s < 2; ++s)
        #pragma unroll
        for (int i = 0; i < 4; ++i) csum[s][i] = 0.f;

    // staging map (R3 verbatim)
    int srow = t >> 5;
    int sg   = t & 31;
    uint4v gx[4];
    #pragma unroll
    for (int j = 0; j < 4; ++j)
        gx[j] = *(const uint4v*)(xTb + (size_t)(j * 16 + srow) * CC + sg * 8);
    #pragma unroll
    for (int j = 0; j < 4; ++j)
        *(uint4v*)(xm + swz8(j * 16 + srow, sg)) = gx[j];
    __syncthreads();

    for (int it = 0; it < 64; ++it) {
        int m0 = it << 6;
        // next-tile staging loads (consumed after G2)
        int m1 = (it < 63 ? (it + 1) : 63) << 6;
        #pragma unroll
        for (int j = 0; j < 4; ++j)
            gx[j] = *(const uint4v*)(xTb + (size_t)(m1 + j * 16 + srow) * CC + sg * 8);
        // xG A-frag loads (R3's tfr pattern, coalesced)
        short8 xg[2][2];             // [ci][kk2]
        #pragma unroll
        for (int ci = 0; ci < 2; ++ci)
            #pragma unroll
            for (int kk2 = 0; kk2 < 2; ++kk2) {
                int cct = wv + 8 * ci;
                xg[ci][kk2] = *(const short8*)(xGb + (size_t)(it * 16 + cct) * 1024
                                               + kk2 * 512 + (t & 63) * 8);
            }
        float invm = invb[m0 + 16 * ms + l15];    // col m = 16ms + l15

        // ---- S = Xq^T Xm from swizzled LDS (R3 verbatim) ----
        short8 bq[8];
        #pragma unroll
        for (int kk = 0; kk < 8; ++kk)
            bq[kk] = *(const short8*)(xm + swz8(16 * ms + l15, kk * 4 + q));
        floatx4 s0a = zero4, s0b = zero4, s1a = zero4, s1b = zero4;
        #pragma unroll
        for (int kk = 0; kk < 8; kk += 2) {
            s0a = mfma16(aq[0][kk],     bq[kk],     s0a);
            s1a = mfma16(aq[1][kk],     bq[kk],     s1a);
            s0b = mfma16(aq[0][kk + 1], bq[kk + 1], s0b);
            s1b = mfma16(aq[1][kk + 1], bq[kk + 1], s1b);
        }
        // ---- P = relu(S*inv)^2 -> pbuf (R3 scalar writes) + csum ----
        #pragma unroll
        for (int s = 0; s < 2; ++s) {
            floatx4 sv = (s == 0) ? (s0a + s0b) : (s1a + s1b);
            unsigned short* pw = &pbuf[2 * np + s][16 * ms + l15];
            #pragma unroll
            for (int i = 0; i < 4; ++i) {
                float v = sv[i] * (invq[s][i] * invm);
                v = fmaxf(v, 0.f);
                v = v * v;
                csum[s][i] += v;
                pw[(q * 4 + i) * 72] = f2bf(v);
            }
        }
        // bar1: P visible + xm reads done (lgkm only; R3 verbatim)
        asm volatile("s_waitcnt lgkmcnt(0)\n\ts_barrier" ::: "memory");

        // ---- Z[c][nq] += Xg * P (R3's G2 with xG as A) ----
        #pragma unroll
        for (int kk2 = 0; kk2 < 2; ++kk2)
            #pragma unroll
            for (int nqs = 0; nqs < 4; ++nqs) {
                short8 pbf = *(const short8*)(&pbuf[nqs][l15 * 72 + kk2 * 32 + q * 8]);
                Zacc[0][nqs] = mfma16(xg[0][kk2], pbf, Zacc[0][nqs]);
                Zacc[1][nqs] = mfma16(xg[1][kk2], pbf, Zacc[1][nqs]);
            }
        // write next tile into xm (R3 verbatim)
        #pragma unroll
        for (int j = 0; j < 4; ++j)
            *(uint4v*)(xm + swz8(j * 16 + srow, sg)) = gx[j];
        // bar2: next tile visible (lgkm only)
        asm volatile("s_waitcnt lgkmcnt(0)\n\ts_barrier" ::: "memory");
    }

    // ---- colsum reduce over l15 (16-lane groups; pure f32) ----
    #pragma unroll
    for (int mask = 1; mask < 16; mask <<= 1)
        #pragma unroll
        for (int s = 0; s < 2; ++s)
            #pragma unroll
            for (int i = 0; i < 4; ++i)
                csum[s][i] += __shfl_xor(csum[s][i], mask, 64);

    __syncthreads();
    // Z -> zbuf (scalar stores, dedicated LDS)
    #pragma unroll
    for (int ci = 0; ci < 2; ++ci) {
        int cct = wv + 8 * ci;
        #pragma unroll
        for (int nqs = 0; nqs < 4; ++nqs)
            #pragma unroll
            for (int i = 0; i < 4; ++i)
                zbuf[(16 * nqs + l15) * 264 + 16 * cct + 4 * q + i] = f2bf(Zacc[ci][nqs][i]);
    }
    if (l15 == 0) {
        #pragma unroll
        for (int s = 0; s < 2; ++s)
            #pragma unroll
            for (int i = 0; i < 4; ++i)
                spbuf2[ms][16 * (2 * np + s) + 4 * q + i] = csum[s][i];
    }
    __syncthreads();

    float svals[4];
    #pragma unroll
    for (int nqs = 0; nqs < 4; ++nqs)
        svals[nqs] = spbuf2[0][16 * nqs + l15] + spbuf2[1][16 * nqs + l15]
                   + spbuf2[2][16 * nqs + l15] + spbuf2[3][16 * nqs + l15];

    // O = W*Z + b*svals
    float* ob = out + (size_t)b * CC * NN;
    floatx4 oa[2][4];
    #pragma unroll
    for (int ci = 0; ci < 2; ++ci) {
        int ct = wv + 8 * ci;
        floatx4 bv = *(const floatx4*)(bias + 16 * ct + 4 * q);
        #pragma unroll
        for (int nqs = 0; nqs < 4; ++nqs)
            #pragma unroll
            for (int i = 0; i < 4; ++i) oa[ci][nqs][i] = bv[i] * svals[nqs];
    }
    #pragma unroll
    for (int kk = 0; kk < 8; ++kk) {
        short8 wf0 = *(const short8*)(wF + (size_t)(wv * 8 + kk) * 512 + (t & 63) * 8);
        short8 wf1 = *(const short8*)(wF + (size_t)((wv + 8) * 8 + kk) * 512 + (t & 63) * 8);
        #pragma unroll
        for (int nqs = 0; nqs < 4; ++nqs) {
            short8 zf = *(const short8*)(&zbuf[(16 * nqs + l15) * 264 + 32 * kk + 8 * q]);
            oa[0][nqs] = mfma16(wf0, zf, oa[0][nqs]);
            oa[1][nqs] = mfma16(wf1, zf, oa[1][nqs]);
        }
    }
    #pragma unroll
    for (int ci = 0; ci < 2; ++ci) {
        int ct = wv + 8 * ci;
        #pragma unroll
        for (int nqs = 0; nqs < 4; ++nqs)
            #pragma unroll
            for (int i = 0; i < 4; ++i)
                ob[(size_t)(16 * ct + 4 * q + i) * NN + n0 + 16 * nqs + l15] = oa[ci][nqs][i];
    }
}

// ---------------------------------------------------------------------------
extern "C" void kernel_launch(void* const* d_in, const int* in_sizes, int n_in,
                              void* d_out, int out_size, void* d_ws, size_t ws_size,
                              hipStream_t stream) {
    const float* x    = (const float*)d_in[0];   // [4,256,64,64]
    const float* Wm   = (const float*)d_in[1];   // [256,256]
    const float* bias = (const float*)d_in[2];   // [256]
    float* out = (float*)d_out;

    // ws: psum 256KB | invn 64KB | xT 8MB | wF 128KB | xG 8MB  (= R3 total)
    char* ws = (char*)d_ws;
    float* psum         = (float*)ws;
    float* invn         = (float*)(ws + 262144);
    unsigned short* xT  = (unsigned short*)(ws + 262144 + 65536);
    unsigned short* wF  = (unsigned short*)(ws + 262144 + 65536 + 8388608);
    unsigned short* xG  = (unsigned short*)(ws + 262144 + 65536 + 8388608 + 131072);

    k_wcast<<<32,   256, 0, stream>>>(Wm, wF);
    k_trans<<<1024, 256, 0, stream>>>(x, xT, psum);
    k_inv  <<<64,   256, 0, stream>>>(psum, invn);
    k_gfrag<<<256,  256, 0, stream>>>(xT, xG);
    k_fused<<<256,  512, 0, stream>>>(xT, xG, wF, bias, invn, out);
}